// Round 1
// baseline (93.633 us; speedup 1.0000x reference)
//
#include <hip/hip_runtime.h>
#include <stdint.h>

// Fused softmax + top-8 (renormalized) over 64 experts.
// Layout: 1 wave = 8 tokens; 8 lanes per token; 8 logits per lane.
// Selection on 64-bit keys: (ordered_float_bits << 6) | (63 - expert_idx)
//  -> larger key == larger logit, ties broken toward LOWER expert index
//     (matches jax.lax.top_k stable tie-break).

static __device__ __forceinline__ uint64_t make_key(float v, int c) {
    uint32_t u = __float_as_uint(v);
    // monotonic map float -> uint32 (increasing)
    uint32_t o = (u & 0x80000000u) ? ~u : (u | 0x80000000u);
    return ((uint64_t)o << 6) | (uint32_t)c;   // c = 63 - expert_idx, 6 bits
}

__global__ __launch_bounds__(256) void topk_softmax_k(
    const float* __restrict__ logits,
    float* __restrict__ out_w,
    float* __restrict__ out_id,
    float* __restrict__ out_tei,
    int T)
{
    const int  lane = threadIdx.x & 63;
    const int  wv   = (int)(threadIdx.x >> 6);
    const long t0   = (long)blockIdx.x * 32 + (long)wv * 8;   // first token of this wave
    if (t0 >= T) return;

    const int  tok_in_grp = lane >> 3;   // which of the wave's 8 tokens
    const int  sub        = lane & 7;    // lane within the token's 8-lane group
    const bool act        = (t0 + tok_in_grp) < T;

    // lane l reads logits[t0*64 + l*8 .. +7] -> wave covers 2KiB contiguous
    const float4* src = reinterpret_cast<const float4*>(logits)
                      + (act ? (t0 * 16 + (long)lane * 2) : 0);
    float4 a = src[0];
    float4 b = src[1];

    const int cb = 63 - sub * 8;  // c for this lane's first expert
    uint64_t k0 = make_key(a.x, cb    );
    uint64_t k1 = make_key(a.y, cb - 1);
    uint64_t k2 = make_key(a.z, cb - 2);
    uint64_t k3 = make_key(a.w, cb - 3);
    uint64_t k4 = make_key(b.x, cb - 4);
    uint64_t k5 = make_key(b.y, cb - 5);
    uint64_t k6 = make_key(b.z, cb - 6);
    uint64_t k7 = make_key(b.w, cb - 7);

    // sort the lane's 8 keys descending: Batcher odd-even merge, 19 comparators
#define CE(x, y) { if (x < y) { uint64_t t_ = x; x = y; y = t_; } }
    CE(k0,k1) CE(k2,k3) CE(k4,k5) CE(k6,k7)
    CE(k0,k2) CE(k1,k3) CE(k4,k6) CE(k5,k7)
    CE(k1,k2) CE(k5,k6)
    CE(k0,k4) CE(k1,k5) CE(k2,k6) CE(k3,k7)
    CE(k2,k4) CE(k3,k5)
    CE(k1,k2) CE(k3,k4) CE(k5,k6)
#undef CE

    // 8 extraction rounds: group-max of lane heads, winner pops its head.
    uint64_t mykey = 0;   // the key this lane outputs (slot k == sub)
    uint64_t mtop  = 0;   // token max key (round 0 winner), known to all lanes
#pragma unroll
    for (int k = 0; k < 8; ++k) {
        uint64_t w = k0;
        #pragma unroll
        for (int m = 1; m <= 4; m <<= 1) {
            uint64_t o = __shfl_xor(w, m, 64);
            if (o > w) w = o;
        }
        if (k == 0) mtop = w;
        if (sub == k) mykey = w;
        if (k0 == w) {  // unique keys -> exactly one lane per group pops
            k0 = k1; k1 = k2; k2 = k3; k3 = k4;
            k4 = k5; k5 = k6; k6 = k7; k7 = 0;
        }
    }

    // decode selected (value, index)
    uint32_t o  = (uint32_t)(mykey >> 6);
    uint32_t ub = (o & 0x80000000u) ? (o & 0x7fffffffu) : ~o;
    float    v  = __uint_as_float(ub);
    int      idx = 63 - (int)(mykey & 63);

    uint32_t om = (uint32_t)(mtop >> 6);
    uint32_t mb = (om & 0x80000000u) ? (om & 0x7fffffffu) : ~om;
    float    mv = __uint_as_float(mb);

    // renormalized weight = exp(v - max) / sum_top8 exp(. - max)
    float e = __expf(v - mv);
    float s = e;
    s += __shfl_xor(s, 1, 64);
    s += __shfl_xor(s, 2, 64);
    s += __shfl_xor(s, 4, 64);
    float wgt = e * __builtin_amdgcn_rcpf(s);

    if (act) {
        const long oi = t0 * 8 + lane;      // == (t0 + tok_in_grp)*8 + sub
        out_w[oi]   = wgt;
        out_id[oi]  = (float)idx;
        out_tei[oi] = (float)oi;            // token_expert_indices == ramp
    }
}

extern "C" void kernel_launch(void* const* d_in, const int* in_sizes, int n_in,
                              void* d_out, int out_size, void* d_ws, size_t ws_size,
                              hipStream_t stream) {
    const float* logits = (const float*)d_in[0];
    const int T = in_sizes[0] / 64;

    float* outw = (float*)d_out;
    float* outi = outw + (size_t)T * 8;
    float* outt = outi + (size_t)T * 8;

    const int blocks = (T + 31) / 32;   // 32 tokens per 256-thread block
    hipLaunchKernelGGL(topk_softmax_k, dim3(blocks), dim3(256), 0, stream,
                       logits, outw, outi, outt, T);
}

// Round 3
// 83.721 us; speedup vs baseline: 1.1184x; 1.1184x over previous
//
#include <hip/hip_runtime.h>
#include <stdint.h>

// Fused softmax + top-8 (renormalized) over 64 experts.
// Layout: 1 wave = 8 tokens; 8 lanes per token; 8 logits per lane.
// Keys: 64-bit (ordered_float_bits << 6) | (63 - expert_idx)
//  -> larger key == larger logit, ties -> lower expert index (jax.lax.top_k).
// All cross-lane ops are within 8-lane groups -> DPP (VALU), no LDS-unit shuffles.

typedef float  f32x4 __attribute__((ext_vector_type(4)));   // clang vector: nontemporal-ok

#define DPP_QUAD_XOR1   0xB1   // quad_perm(1,0,3,2)  : lane ^ 1
#define DPP_QUAD_XOR2   0x4E   // quad_perm(2,3,0,1)  : lane ^ 2
#define DPP_HALF_MIRROR 0x141  // row_half_mirror     : lane <-> 7-lane (within 8)

template<int CTRL>
static __device__ __forceinline__ uint64_t dpp64(uint64_t x) {
    int lo = __builtin_amdgcn_update_dpp(0, (int)(uint32_t)x,         CTRL, 0xF, 0xF, true);
    int hi = __builtin_amdgcn_update_dpp(0, (int)(uint32_t)(x >> 32), CTRL, 0xF, 0xF, true);
    return ((uint64_t)(uint32_t)hi << 32) | (uint32_t)lo;
}

template<int CTRL>
static __device__ __forceinline__ float dppf(float x) {
    int i = __builtin_amdgcn_update_dpp(0, __float_as_int(x), CTRL, 0xF, 0xF, true);
    return __int_as_float(i);
}

static __device__ __forceinline__ uint64_t make_key(float v, int c) {
    uint32_t u = __float_as_uint(v);
    uint32_t o = (u & 0x80000000u) ? ~u : (u | 0x80000000u);  // monotonic map
    return ((uint64_t)o << 6) | (uint32_t)c;                   // c = 63 - idx
}

__global__ __launch_bounds__(256) void topk_softmax_k(
    const float* __restrict__ logits,
    float* __restrict__ out_w,
    float* __restrict__ out_id,
    float* __restrict__ out_tei,
    int T)
{
    const int  lane = threadIdx.x & 63;
    const int  wv   = (int)(threadIdx.x >> 6);
    const long t0   = (long)blockIdx.x * 32 + (long)wv * 8;   // first token of wave
    if (t0 >= T) return;

    const int  tok_in_grp = lane >> 3;
    const int  sub        = lane & 7;
    const bool act        = (t0 + tok_in_grp) < T;

    // lane l reads logits[t0*64 + l*8 .. +7] -> wave covers 2KiB contiguous
    const f32x4* src = reinterpret_cast<const f32x4*>(logits)
                     + (act ? (t0 * 16 + (long)lane * 2) : 0);
    f32x4 a = __builtin_nontemporal_load(src);
    f32x4 b = __builtin_nontemporal_load(src + 1);

    const int cb = 63 - sub * 8;
    uint64_t k0 = make_key(a.x, cb    );
    uint64_t k1 = make_key(a.y, cb - 1);
    uint64_t k2 = make_key(a.z, cb - 2);
    uint64_t k3 = make_key(a.w, cb - 3);
    uint64_t k4 = make_key(b.x, cb - 4);
    uint64_t k5 = make_key(b.y, cb - 5);
    uint64_t k6 = make_key(b.z, cb - 6);
    uint64_t k7 = make_key(b.w, cb - 7);

    // sort the lane's 8 keys descending: Batcher odd-even merge, 19 comparators
#define CE(x, y) { if (x < y) { uint64_t t_ = x; x = y; y = t_; } }
    CE(k0,k1) CE(k2,k3) CE(k4,k5) CE(k6,k7)
    CE(k0,k2) CE(k1,k3) CE(k4,k6) CE(k5,k7)
    CE(k1,k2) CE(k5,k6)
    CE(k0,k4) CE(k1,k5) CE(k2,k6) CE(k3,k7)
    CE(k2,k4) CE(k3,k5)
    CE(k1,k2) CE(k3,k4) CE(k5,k6)
#undef CE

    // 8 extraction rounds: DPP butterfly max of 8 lane-heads, winner pops.
    uint64_t mykey = 0;   // key this lane outputs (slot k == sub)
    uint64_t mtop  = 0;   // token max key (round 0), known to all lanes
#pragma unroll
    for (int k = 0; k < 8; ++k) {
        uint64_t w = k0;
        { uint64_t o = dpp64<DPP_QUAD_XOR1>(w);   if (o > w) w = o; }
        { uint64_t o = dpp64<DPP_QUAD_XOR2>(w);   if (o > w) w = o; }
        { uint64_t o = dpp64<DPP_HALF_MIRROR>(w); if (o > w) w = o; }
        if (k == 0) mtop = w;
        if (sub == k) mykey = w;
        if (k0 == w) {  // unique keys -> exactly one lane per group pops
            k0 = k1; k1 = k2; k2 = k3; k3 = k4;
            k4 = k5; k5 = k6; k6 = k7; k7 = 0;
        }
    }

    // decode selected (value, index)
    uint32_t o  = (uint32_t)(mykey >> 6);
    uint32_t ub = (o & 0x80000000u) ? (o & 0x7fffffffu) : ~o;
    float    v  = __uint_as_float(ub);
    int      idx = 63 - (int)(mykey & 63);

    uint32_t om = (uint32_t)(mtop >> 6);
    uint32_t mb = (om & 0x80000000u) ? (om & 0x7fffffffu) : ~om;
    float    mv = __uint_as_float(mb);

    // renormalized weight = exp(v - max) / sum_top8 exp(. - max)
    float e = __expf(v - mv);
    float s = e;
    s += dppf<DPP_QUAD_XOR1>(s);
    s += dppf<DPP_QUAD_XOR2>(s);
    s += dppf<DPP_HALF_MIRROR>(s);
    float wgt = e / s;   // exact IEEE divide

    if (act) {
        const long oi = t0 * 8 + lane;      // == (t0 + tok_in_grp)*8 + sub
        __builtin_nontemporal_store(wgt,        &out_w[oi]);
        __builtin_nontemporal_store((float)idx, &out_id[oi]);
        __builtin_nontemporal_store((float)oi,  &out_tei[oi]);
    }
}

extern "C" void kernel_launch(void* const* d_in, const int* in_sizes, int n_in,
                              void* d_out, int out_size, void* d_ws, size_t ws_size,
                              hipStream_t stream) {
    const float* logits = (const float*)d_in[0];
    const int T = in_sizes[0] / 64;

    float* outw = (float*)d_out;
    float* outi = outw + (size_t)T * 8;
    float* outt = outi + (size_t)T * 8;

    const int blocks = (T + 31) / 32;   // 32 tokens per 256-thread block
    hipLaunchKernelGGL(topk_softmax_k, dim3(blocks), dim3(256), 0, stream,
                       logits, outw, outi, outt, T);
}

// Round 4
// 78.120 us; speedup vs baseline: 1.1986x; 1.0717x over previous
//
#include <hip/hip_runtime.h>
#include <stdint.h>

// Fused softmax + top-8 (renormalized) over 64 experts.
// Layout: 1 wave = 8 tokens; 8 lanes per token; 8 logits per lane.
// Keys: exact f64 = (double)(monotonic_u32(logit)) + (63-expert_idx)/64
//   38 significant bits << 53-bit mantissa -> EXACT ordering, ties -> lower
//   expert index (matches jax.lax.top_k stable tie-break).
// Selection: per-lane sort-8, then 3-level symmetric bitonic merge via DPP
//   (xor1, xor2, half-mirror). After 3 levels every lane of the 8-lane group
//   holds the global top-8 in descending order -> no serial extraction loop.

typedef float f32x4 __attribute__((ext_vector_type(4)));

#define DPP_QUAD_XOR1   0xB1   // quad_perm(1,0,3,2)  : lane ^ 1
#define DPP_QUAD_XOR2   0x4E   // quad_perm(2,3,0,1)  : lane ^ 2
#define DPP_HALF_MIRROR 0x141  // row_half_mirror     : lane <-> 7-lane (in 8)

template<int CTRL>
static __device__ __forceinline__ double dpp64d(double x) {
    uint64_t b = (uint64_t)__double_as_longlong(x);
    int lo = __builtin_amdgcn_update_dpp(0, (int)(uint32_t)b,         CTRL, 0xF, 0xF, true);
    int hi = __builtin_amdgcn_update_dpp(0, (int)(uint32_t)(b >> 32), CTRL, 0xF, 0xF, true);
    uint64_t r = ((uint64_t)(uint32_t)hi << 32) | (uint32_t)lo;
    return __longlong_as_double((long long)r);
}

template<int CTRL>
static __device__ __forceinline__ float dppf(float x) {
    int i = __builtin_amdgcn_update_dpp(0, __float_as_int(x), CTRL, 0xF, 0xF, true);
    return __int_as_float(i);
}

// compare-exchange, descending (max stays in x): v_max_f64 + v_min_f64
#define CED(x, y) { double hi_ = fmax(x, y), lo_ = fmin(x, y); x = hi_; y = lo_; }

template<int CTRL>
static __device__ __forceinline__ void merge_level(double k[8]) {
    // Batcher half-cleaner with partner's list reversed (register-renumbered,
    // so the reversal is free): m[i] = max(own[i], partner[7-i]).
    // m is the top-8 of the union, bitonic.
    double m[8];
#pragma unroll
    for (int i = 0; i < 8; ++i) {
        double p = dpp64d<CTRL>(k[7 - i]);
        m[i] = fmax(k[i], p);
    }
    // bitonic clean -> descending
    CED(m[0], m[4]) CED(m[1], m[5]) CED(m[2], m[6]) CED(m[3], m[7])
    CED(m[0], m[2]) CED(m[1], m[3]) CED(m[4], m[6]) CED(m[5], m[7])
    CED(m[0], m[1]) CED(m[2], m[3]) CED(m[4], m[5]) CED(m[6], m[7])
#pragma unroll
    for (int i = 0; i < 8; ++i) k[i] = m[i];
}

__global__ __launch_bounds__(256) void topk_softmax_k(
    const float* __restrict__ logits,
    float* __restrict__ out_w,
    float* __restrict__ out_id,
    float* __restrict__ out_tei,
    int T)
{
    const int  lane = threadIdx.x & 63;
    const int  wv   = (int)(threadIdx.x >> 6);
    const long t0   = (long)blockIdx.x * 32 + (long)wv * 8;   // first token of wave
    if (t0 >= T) return;

    const int  sub = lane & 7;
    const bool act = (t0 + (lane >> 3)) < T;

    // lane l reads logits[t0*64 + l*8 .. +7] -> wave covers 2KiB contiguous
    const f32x4* src = reinterpret_cast<const f32x4*>(logits)
                     + (act ? (t0 * 16 + (long)lane * 2) : 0);
    f32x4 a = __builtin_nontemporal_load(src);
    f32x4 b = __builtin_nontemporal_load(src + 1);

    const float vals[8] = {a.x, a.y, a.z, a.w, b.x, b.y, b.z, b.w};
    const double base = (double)(63 - sub * 8) * 0.015625;  // cidx0/64, exact

    double k[8];
#pragma unroll
    for (int j = 0; j < 8; ++j) {
        uint32_t u = __float_as_uint(vals[j]);
        uint32_t o = (u & 0x80000000u) ? ~u : (u | 0x80000000u);  // monotonic
        k[j] = (double)o + (base - j * 0.015625);                  // exact dyadic
    }

    // sort lane's 8 keys descending: Batcher odd-even merge, 19 comparators
    CED(k[0],k[1]) CED(k[2],k[3]) CED(k[4],k[5]) CED(k[6],k[7])
    CED(k[0],k[2]) CED(k[1],k[3]) CED(k[4],k[6]) CED(k[5],k[7])
    CED(k[1],k[2]) CED(k[5],k[6])
    CED(k[0],k[4]) CED(k[1],k[5]) CED(k[2],k[6]) CED(k[3],k[7])
    CED(k[2],k[4]) CED(k[3],k[5])
    CED(k[1],k[2]) CED(k[3],k[4]) CED(k[5],k[6])

    // 3-level symmetric merge: after this every lane holds global top-8 desc.
    merge_level<DPP_QUAD_XOR1>(k);
    merge_level<DPP_QUAD_XOR2>(k);
    merge_level<DPP_HALF_MIRROR>(k);

    // lane `sub` outputs slot `sub`: binary select tree (static indices only)
    double t4a = (sub & 4) ? k[4] : k[0];
    double t4b = (sub & 4) ? k[5] : k[1];
    double t4c = (sub & 4) ? k[6] : k[2];
    double t4d = (sub & 4) ? k[7] : k[3];
    double t2a = (sub & 2) ? t4c : t4a;
    double t2b = (sub & 2) ? t4d : t4b;
    double sel = (sub & 1) ? t2b : t2a;

    // decode max (slot 0) value
    uint32_t o0 = (uint32_t)k[0];
    uint32_t mb = (o0 & 0x80000000u) ? (o0 & 0x7fffffffu) : ~o0;
    float    mv = __uint_as_float(mb);

    // decode own slot (value, index)
    uint32_t os   = (uint32_t)sel;               // trunc = floor (sel > 0)
    double   frac = sel - (double)os;
    int      cidx = (int)(frac * 64.0 + 0.5);    // frac*64 is an exact integer
    int      idx  = 63 - cidx;
    uint32_t ub   = (os & 0x80000000u) ? (os & 0x7fffffffu) : ~os;
    float    v    = __uint_as_float(ub);

    // renormalized weight = exp(v - max) / sum_top8 exp(. - max)
    float e = __expf(v - mv);
    float s = e;
    s += dppf<DPP_QUAD_XOR1>(s);
    s += dppf<DPP_QUAD_XOR2>(s);
    s += dppf<DPP_HALF_MIRROR>(s);
    float wgt = e * __builtin_amdgcn_rcpf(s);

    if (act) {
        const long oi = t0 * 8 + lane;           // == token*8 + sub
        __builtin_nontemporal_store(wgt,        &out_w[oi]);
        __builtin_nontemporal_store((float)idx, &out_id[oi]);
        __builtin_nontemporal_store((float)oi,  &out_tei[oi]);
    }
}

extern "C" void kernel_launch(void* const* d_in, const int* in_sizes, int n_in,
                              void* d_out, int out_size, void* d_ws, size_t ws_size,
                              hipStream_t stream) {
    const float* logits = (const float*)d_in[0];
    const int T = in_sizes[0] / 64;

    float* outw = (float*)d_out;
    float* outi = outw + (size_t)T * 8;
    float* outt = outi + (size_t)T * 8;

    const int blocks = (T + 31) / 32;   // 32 tokens per 256-thread block
    hipLaunchKernelGGL(topk_softmax_k, dim3(blocks), dim3(256), 0, stream,
                       logits, outw, outi, outt, T);
}